// Round 8
// baseline (1946.908 us; speedup 1.0000x reference)
//
#include <hip/hip_runtime.h>

#define T_SEQ 1024
#define NBATCH 256
#define DIN 128
#define HID 64
#define DOUT 128

// ---------------- LDS layouts ----------------
// Encoder (unchanged from R7): buffers of 256 floats: X @0(128) | H0 @128(64) | H1 @192(64)
//   K-split interleaved by f4 (thread half q owns f4 elems {2i+q}) -> conflict-free.
// Decoder (new, role-split): DH0[64] h0(t); DH1[2][64] h1 double-slot (parity t&1);
//   PA[256] = dU0·h0 partials (written in B, consumed next A);
//   PB[256] = dU1·h1 partials (written in A, consumed in B).
//   Lower waves (tid<256): full-K gate-row dots + in-lane cell (quad DPP).
//   Upper waves: partial dots + 2-way-split fc.
#define TWO_LOG2E 2.8853900817779268f   // 2*log2(e)

typedef float v2f __attribute__((ext_vector_type(2)));

__device__ __forceinline__ float rcp_f(float x) { return __builtin_amdgcn_rcpf(x); }

__device__ __forceinline__ float exp2_f(float x) {
#if __has_builtin(__builtin_amdgcn_exp2f)
  return __builtin_amdgcn_exp2f(x);
#else
  return exp2f(x);
#endif
}

// tanh(x) with pre-scaled argument y = x*TWO_LOG2E:  tanh = 1 - 2/(1+2^y); inf-safe
__device__ __forceinline__ float tanh_pre(float y) {
  float m = exp2_f(y);
  return fmaf(-2.0f, rcp_f(1.0f + m), 1.0f);
}
__device__ __forceinline__ float tanh_full(float x) { return tanh_pre(x * TWO_LOG2E); }

// quad-perm DPP butterfly add (lane^1: 0xB1) on the VALU pipe
template<int CTRL>
__device__ __forceinline__ float dpp_add(float v) {
  int p = __builtin_amdgcn_update_dpp(0, __float_as_int(v), CTRL, 0xF, 0xF, true);
  return v + __int_as_float(p);
}

// DPP mov row_shl:N (0x100|N): dst lane i <- src lane i+N within 16-lane row
template<int CTRL>
__device__ __forceinline__ float dpp_mov(float v) {
  int p = __builtin_amdgcn_update_dpp(0, __float_as_int(v), CTRL, 0xF, 0xF, true);
  return __int_as_float(p);
}

// LDS-only barrier: do NOT drain vmcnt (x prefetch loads / out stores stay in flight).
__device__ __forceinline__ void bar_lds() {
  asm volatile("s_waitcnt lgkmcnt(0)\n\ts_barrier" ::: "memory");
}

template<int N4>
__device__ __forceinline__ void loadrow(float* w, const float* p) {
#pragma unroll
  for (int k = 0; k < N4; ++k) {
    float4 q = ((const float4*)p)[k];
    w[4*k+0] = q.x; w[4*k+1] = q.y; w[4*k+2] = q.z; w[4*k+3] = q.w;
  }
}

// Interleaved weight load (encoder): thread's w f4-slot i <- row f4 element (2i+q).
template<int N4>
__device__ __forceinline__ void loadrow_il(float* w, const float* p, int q) {
#pragma unroll
  for (int i = 0; i < N4; ++i) {
    float4 v = ((const float4*)p)[2 * i + q];
    w[4*i+0] = v.x; w[4*i+1] = v.y; w[4*i+2] = v.z; w[4*i+3] = v.w;
  }
}

// Packed-fp32 dot over K4 float4 elements (uniform or per-lane addresses).
template<int K4>
__device__ __forceinline__ float dotp(const float* wf, const float4* v) {
  const v2f* w = (const v2f*)wf;
  v2f a0 = {0.f,0.f}, a1 = {0.f,0.f};
#pragma unroll
  for (int k = 0; k < K4; ++k) {
    float4 qv = v[k];
    v2f q0 = {qv.x, qv.y};
    v2f q1 = {qv.z, qv.w};
    a0 = __builtin_elementwise_fma(w[2*k+0], q0, a0);
    a1 = __builtin_elementwise_fma(w[2*k+1], q1, a1);
  }
  v2f s = a0 + a1;
  return s.x + s.y;
}

// Encoder cell (R7 lane map): q=tid&1, g=(tid>>1)&3, j=tid>>3; 8-lane group lanes 0,1=i;
// 2,3=f; 4,5=g~; 6,7=o. Gather via row_shl:2/4/6; c/h valid in lanes 0,1 of each group.
__device__ __forceinline__ float cell_update(float pre, float gsc, float gscl, float gof, float& c) {
  float a  = fmaf(gsc, tanh_pre(pre * gscl), gof);
  float f_s = dpp_mov<0x102>(a);
  float g_t = dpp_mov<0x104>(a);
  float o_s = dpp_mov<0x106>(a);
  c = fmaf(f_s, c, a * g_t);
  return o_s * tanh_full(c);
}

// Decoder cell (quad lane map): gates i,f,g~,o of unit u in lanes 4u..4u+3.
// Gather via row_shl:1/2/3; c/h valid in lane 4u (tid&3==0).
__device__ __forceinline__ float cell4(float pre, float gsc, float gscl, float gof, float& c) {
  float a  = fmaf(gsc, tanh_pre(pre * gscl), gof);
  float f_s = dpp_mov<0x101>(a);
  float g_t = dpp_mov<0x102>(a);
  float o_s = dpp_mov<0x103>(a);
  c = fmaf(f_s, c, a * g_t);
  return o_s * tanh_full(c);
}

// ---------------- prep kernel: C0 = dWih0 @ fcW  [256x64], fcbt = dWih0 @ fcb ----------------
__global__ void prep_kernel(const float* __restrict__ dWih0,
                            const float* __restrict__ fcW,
                            const float* __restrict__ fcb,
                            float* __restrict__ ws) {
  const int r = (int)blockIdx.x;           // 256 blocks
  const int jj = (int)threadIdx.x;         // 64 threads
  const float* wr = dWih0 + (size_t)r * DIN;
  float acc = 0.f;
  for (int o = 0; o < DIN; ++o) acc = fmaf(wr[o], fcW[(size_t)o * HID + jj], acc);
  ws[(size_t)r * HID + jj] = acc;
  if (jj == 0) {
    float a = 0.f;
    for (int o = 0; o < DIN; ++o) a = fmaf(wr[o], fcb[o], a);
    ws[256 * HID + r] = a;
  }
}

// ---------------- main persistent kernel: 1 block / batch element, 512 threads ----------------
__global__ __launch_bounds__(512, 2) void lstm_ae_kernel(
    const float* __restrict__ x,
    const float* __restrict__ eW0, const float* __restrict__ eU0,
    const float* __restrict__ ebi0, const float* __restrict__ ebh0,
    const float* __restrict__ eW1, const float* __restrict__ eU1,
    const float* __restrict__ ebi1, const float* __restrict__ ebh1,
    const float* __restrict__ dW0, const float* __restrict__ dU0,
    const float* __restrict__ dbi0, const float* __restrict__ dbh0,
    const float* __restrict__ dW1, const float* __restrict__ dU1,
    const float* __restrict__ dbi1, const float* __restrict__ dbh1,
    const float* __restrict__ fcW, const float* __restrict__ fcb,
    const float* __restrict__ ws,
    float* __restrict__ out)
{
  __shared__ __align__(16) float Abuf[256];
  __shared__ __align__(16) float Bbuf[256];
  __shared__ __align__(16) float DH0[64];
  __shared__ __align__(16) float DH1[2][64];
  __shared__ __align__(16) float PA[256];
  __shared__ __align__(16) float PB[256];
  __shared__ __align__(16) float CT0[64];
  __shared__ __align__(16) float CT1[64];

  const int tid = (int)threadIdx.x;
  const int b   = (int)blockIdx.x;
  const int q   = tid & 1;
  const int g   = (tid >> 1) & 3;
  const int r   = g * HID + (tid >> 3);
  const int l8  = tid & 7;

  const float gsc  = (g == 2) ? 1.0f : 0.5f;
  const float gof  = (g == 2) ? 0.0f : 0.5f;
  const float gscl = gsc * TWO_LOG2E;

  float w[160];

  // ---------------- encoder weights (interleaved q-split of each K-chunk, 1 row/thread) ----------------
  loadrow_il<16>(w,       eW0 + (size_t)r * DIN, q);   // L0 x-part   (64 floats)
  loadrow_il<8> (w + 64,  eU0 + (size_t)r * HID, q);   // L0 h0-part  (32)
  loadrow_il<8> (w + 96,  eW1 + (size_t)r * HID, q);   // L1 h0-part  (32)
  loadrow_il<8> (w + 128, eU1 + (size_t)r * HID, q);   // L1 h1-part  (32)
  float bs0 = ebi0[r] + ebh0[r];
  float bs1 = ebi1[r] + ebh1[r];

  const float* xb = x + (size_t)b * (T_SEQ * DIN);
  float* outb     = out + (size_t)b * (T_SEQ * DOUT);

  // init: A = [x0 | h0(-1)=0 | h1(-2)=0]; B.H1 = h1(-1) = 0
  if (tid < 32) ((float4*)Abuf)[tid] = ((const float4*)xb)[tid];
  if (tid >= 128 && tid < 256) Abuf[tid] = 0.f;
  if (tid >= 192 && tid < 256) Bbuf[tid] = 0.f;
  float4 xcar{};
  if (tid < 32) xcar = ((const float4*)(xb + DIN))[tid];   // x(1) in flight
  float c0 = 0.f, c1 = 0.f;
  __syncthreads();

  // ---------------- phase 1: layer-skewed fused encoder (ONE barrier per phase) ----------------
  auto enc_phase = [&](float* R, float* W, int t) {
    if (tid < 32 && t + 1 < T_SEQ) ((float4*)W)[tid] = xcar;       // stage x(t+1)
    if (tid < 32 && t + 2 < T_SEQ)
      xcar = ((const float4*)(xb + (size_t)(t + 2) * DIN))[tid];   // issue x(t+2)
    const float4* R4 = (const float4*)R;
    const v2f* wx  = (const v2f*)(w);
    const v2f* wh  = (const v2f*)(w + 64);
    const v2f* w1h = (const v2f*)(w + 96);
    const v2f* w1g = (const v2f*)(w + 128);
    v2f p0a = {0.f,0.f}, p0b = {0.f,0.f}, p1a = {0.f,0.f}, p1b = {0.f,0.f};
#pragma unroll
    for (int k = 0; k < 16; ++k) {                                  // x chunk (L0 only)
      float4 qv = R4[2 * k + q]; v2f q0 = {qv.x, qv.y}, q1 = {qv.z, qv.w};
      p0a = __builtin_elementwise_fma(wx[2*k],   q0, p0a);
      p0b = __builtin_elementwise_fma(wx[2*k+1], q1, p0b);
    }
#pragma unroll
    for (int k = 0; k < 8; ++k) {                                   // h0 chunk (L0 AND L1)
      float4 qv = R4[32 + 2 * k + q]; v2f q0 = {qv.x, qv.y}, q1 = {qv.z, qv.w};
      p0a = __builtin_elementwise_fma(wh[2*k],    q0, p0a);
      p0b = __builtin_elementwise_fma(wh[2*k+1],  q1, p0b);
      p1a = __builtin_elementwise_fma(w1h[2*k],   q0, p1a);
      p1b = __builtin_elementwise_fma(w1h[2*k+1], q1, p1b);
    }
#pragma unroll
    for (int k = 0; k < 8; ++k) {                                   // h1 chunk (L1 only)
      float4 qv = R4[48 + 2 * k + q]; v2f q0 = {qv.x, qv.y}, q1 = {qv.z, qv.w};
      p1a = __builtin_elementwise_fma(w1g[2*k],   q0, p1a);
      p1b = __builtin_elementwise_fma(w1g[2*k+1], q1, p1b);
    }
    v2f s0 = p0a + p0b, s1 = p1a + p1b;
    float p0 = dpp_add<0xB1>(s0.x + s0.y) + bs0;
    float p1 = dpp_add<0xB1>(s1.x + s1.y) + bs1;
    float h0v = cell_update(p0, gsc, gscl, gof, c0);
    float c1n = c1;
    float h1v = cell_update(p1, gsc, gscl, gof, c1n);
    if (l8 == 0) W[128 + (tid >> 3)] = h0v;        // h0(t)
    if (t > 0) {                                   // t=0: h1(-1)/c1 stay at zero init
      c1 = c1n;
      if (l8 == 1) W[192 + (tid >> 3)] = h1v;      // h1(t-1)
    }
    bar_lds();
  };

#pragma unroll 1
  for (int t = 0; t < T_SEQ; t += 2) {
    enc_phase(Abuf, Bbuf, t);
    enc_phase(Bbuf, Abuf, t + 1);
  }
  // encoder epilogue: h1(1023) from A = [h0(1023) | h1(1022)]
  {
    const float4* R4 = (const float4*)Abuf;
    const v2f* w1h = (const v2f*)(w + 96);
    const v2f* w1g = (const v2f*)(w + 128);
    v2f p1a = {0.f,0.f}, p1b = {0.f,0.f};
#pragma unroll
    for (int k = 0; k < 8; ++k) {
      float4 qv = R4[32 + 2 * k + q]; v2f q0 = {qv.x, qv.y}, q1 = {qv.z, qv.w};
      p1a = __builtin_elementwise_fma(w1h[2*k],   q0, p1a);
      p1b = __builtin_elementwise_fma(w1h[2*k+1], q1, p1b);
    }
#pragma unroll
    for (int k = 0; k < 8; ++k) {
      float4 qv = R4[48 + 2 * k + q]; v2f q0 = {qv.x, qv.y}, q1 = {qv.z, qv.w};
      p1a = __builtin_elementwise_fma(w1g[2*k],   q0, p1a);
      p1b = __builtin_elementwise_fma(w1g[2*k+1], q1, p1b);
    }
    v2f s1 = p1a + p1b;
    float p1 = dpp_add<0xB1>(s1.x + s1.y) + bs1;
    float h1v = cell_update(p1, gsc, gscl, gof, c1);
    bar_lds();                                     // reads of old h1 slot done before overwrite
    if (l8 == 0) Abuf[192 + (tid >> 3)] = h1v;
  }
  __syncthreads();

  // ---------------- transition: states to decoder layout (old lane map -> slots) ----------------
  if (tid < 64)       DH0[tid]         = tanh_full(Abuf[128 + tid]);       // h0dec(-1)
  else if (tid < 128) DH1[1][tid - 64] = tanh_full(Abuf[192 + (tid - 64)]); // h1dec(-1) (slot 1)
  if ((tid & 7) == 0) {                      // lanes holding valid c (old map), one per unit
    int ju = tid >> 3;
    CT0[ju] = tanh_full(c0);
    CT1[ju] = tanh_full(c1);
  }

  // ---------------- decoder weights (role-split, full-K rows) ----------------
  const bool lower = (tid < 256);            // waves 0-3: gate-rows; waves 4-7: partials+fc
  const int  tu = tid - 256;
  const int  ud = tid >> 2;                  // lower: unit (0..63)
  const int  gd = tid & 3;                   // lower: gate
  const int  rd = gd * HID + ud;             // lower: row index (valid for tid<256)
  const int  ru = (tu & 3) * HID + ((tid >> 2) & 63);   // upper: partial row index
  const int  fr = tu >> 1;                   // upper: fc output row (0..127)
  const int  fh = tu & 1;                    // upper: fc K-half

  const float gscd  = (gd == 2) ? 1.0f : 0.5f;
  const float gofd  = (gd == 2) ? 0.0f : 0.5f;
  const float gscld = gscd * TWO_LOG2E;

  const float* C0 = ws;
  const float* fcbt_arr = ws + 256 * HID;
  float bs0d = 0.f, bs1d = 0.f, fcbt = 0.f, fb = 0.f;
  if (lower) {
    loadrow<16>(w,      C0  + (size_t)rd * HID);   // C0 row (L0 vs h1)
    loadrow<16>(w + 64, dW1 + (size_t)rd * HID);   // dW1 row (L1 vs h0)
    bs0d = dbi0[rd] + dbh0[rd];
    bs1d = dbi1[rd] + dbh1[rd];
    fcbt = fcbt_arr[rd];
  } else {
    loadrow<16>(w,       dU1 + (size_t)ru * HID);  // dU1 row (PB partial)
    loadrow<16>(w + 64,  dU0 + (size_t)ru * HID);  // dU0 row (PA partial)
    loadrow<8> (w + 128, fcW + (size_t)fr * HID + fh * 32);  // fc half-row
    fb = fcb[fr];
  }
  __syncthreads();

  // prologue P: c-state pickup + PA init from h0dec(-1)
  float c0r = 0.f, c1r = 0.f;
  if (lower) {
    c0r = CT0[ud];
    c1r = CT1[ud];
  } else {
    PA[ru] = dotp<16>(w + 64, (const float4*)DH0);
  }
  bar_lds();

  // ---------------- phase 2: autoregressive decoder (role-split, 2 barriers/step) ----------------
  auto decA = [&](int t, const float* h1r) {
    if (lower) {
      float p0 = dotp<16>(w, (const float4*)h1r) + PA[rd] + bs0d + fcbt;
      float h0v = cell4(p0, gscd, gscld, gofd, c0r);
      if (gd == 0) DH0[ud] = h0v;
    } else {
      PB[ru] = dotp<16>(w, (const float4*)h1r);
    }
    bar_lds();
  };
  auto decB = [&](int t, const float* h1r, float* h1w) {
    if (lower) {
      float p1 = dotp<16>(w + 64, (const float4*)DH0) + PB[rd] + bs1d;
      float h1v = cell4(p1, gscd, gscld, gofd, c1r);
      if (gd == 0) h1w[ud] = h1v;
    } else {
      PA[ru] = dotp<16>(w + 64, (const float4*)DH0);
      float s = dotp<8>(w + 128, (const float4*)h1r + fh * 8);
      s = dpp_add<0xB1>(s);
      if ((tu & 1) == 0 && t > 0) outb[(size_t)(t - 1) * DOUT + fr] = s + fb;
    }
    bar_lds();
  };

  // step 0 peeled: x(0)=pred(-1)=0 -> no C0 term, no fcbt; fc output skipped in B(0)
  {
    if (lower) {
      float p0 = PA[rd] + bs0d;
      float h0v = cell4(p0, gscd, gscld, gofd, c0r);
      if (gd == 0) DH0[ud] = h0v;
    } else {
      PB[ru] = dotp<16>(w, (const float4*)DH1[1]);   // dU1 . h1dec(-1)
    }
    bar_lds();
    decB(0, DH1[1], DH1[0]);                          // h1(0) -> slot 0
  }
#pragma unroll 1
  for (int t = 1; t < T_SEQ - 1; t += 2) {
    decA(t,     DH1[0]); decB(t,     DH1[0], DH1[1]);   // odd t: read slot0, write slot1
    decA(t + 1, DH1[1]); decB(t + 1, DH1[1], DH1[0]);   // even:  read slot1, write slot0
  }
  decA(T_SEQ - 1, DH1[0]); decB(T_SEQ - 1, DH1[0], DH1[1]);   // t=1023

  // epilogue: pred(1023) from h1(1023) @ DH1[1]
  if (!lower) {
    float s = dotp<8>(w + 128, (const float4*)DH1[1] + fh * 8);
    s = dpp_add<0xB1>(s);
    if ((tu & 1) == 0) outb[(size_t)(T_SEQ - 1) * DOUT + fr] = s + fb;
  }
}

extern "C" void kernel_launch(void* const* d_in, const int* in_sizes, int n_in,
                              void* d_out, int out_size, void* d_ws, size_t ws_size,
                              hipStream_t stream) {
  (void)in_sizes; (void)n_in; (void)ws_size; (void)out_size;
  const float* x    = (const float*)d_in[0];
  const float* eW0  = (const float*)d_in[1];
  const float* eU0  = (const float*)d_in[2];
  const float* ebi0 = (const float*)d_in[3];
  const float* ebh0 = (const float*)d_in[4];
  const float* eW1  = (const float*)d_in[5];
  const float* eU1  = (const float*)d_in[6];
  const float* ebi1 = (const float*)d_in[7];
  const float* ebh1 = (const float*)d_in[8];
  const float* dW0  = (const float*)d_in[9];
  const float* dU0  = (const float*)d_in[10];
  const float* dbi0 = (const float*)d_in[11];
  const float* dbh0 = (const float*)d_in[12];
  const float* dW1  = (const float*)d_in[13];
  const float* dU1  = (const float*)d_in[14];
  const float* dbi1 = (const float*)d_in[15];
  const float* dbh1 = (const float*)d_in[16];
  const float* fcW  = (const float*)d_in[17];
  const float* fcb  = (const float*)d_in[18];
  float* ws  = (float*)d_ws;
  float* out = (float*)d_out;

  hipLaunchKernelGGL(prep_kernel, dim3(256), dim3(64), 0, stream, dW0, fcW, fcb, ws);
  hipLaunchKernelGGL(lstm_ae_kernel, dim3(NBATCH), dim3(512), 0, stream,
                     x, eW0, eU0, ebi0, ebh0, eW1, eU1, ebi1, ebh1,
                     dW0, dU0, dbi0, dbh0, dW1, dU1, dbi1, dbh1,
                     fcW, fcb, ws, out);
}